// Round 8
// baseline (103.358 us; speedup 1.0000x reference)
//
#include <hip/hip_runtime.h>

#define T_LEN   524288
#define BATCH   32
#define WIN     1024
#define STRIDE  256
#define NCODE   32
#define NFRAMES 2049                 // T_LEN/STRIDE + 1
#define NFR_TOT (BATCH * NFRAMES)    // 65568 frames
#define NBLK    2048                 // 256-sample product-blocks per row
#define NG      (BATCH * NBLK)       // 65536 block-product groups

// ---------------------------------------------------------------------------
// EXACT r3 source (41.8 µs anchor). This round is an amplification ablation:
// pass 1 is launched 4x (identical writes, deterministic) so that
// dur(r8) - dur(r3) = 3 * t(pass1), with overhead and pass 2 cancelling.
// ---------------------------------------------------------------------------
__global__ __launch_bounds__(256) void blockprod_kernel(const float* __restrict__ in,
                                                        float* __restrict__ B) {
    const int tid = blockIdx.x * 256 + threadIdx.x;
    const int g   = tid >> 2;            // (b, i) group
    const int s   = tid & 3;
    const int b   = g >> 11;             // NBLK = 2048
    const int i   = g & (NBLK - 1);
    const float* row = in + (size_t)b * T_LEN;
    const int m0 = i * 256 + s * 64;     // reads [m0, m0+96)

    float w[96];
    if (m0 + 96 <= T_LEN) {
        #pragma unroll
        for (int q = 0; q < 24; ++q) {
            const float4 v = *reinterpret_cast<const float4*>(row + m0 + 4 * q);
            w[4*q] = v.x; w[4*q+1] = v.y; w[4*q+2] = v.z; w[4*q+3] = v.w;
        }
    } else {                             // last block, last lane: zero-pad
        #pragma unroll
        for (int q = 0; q < 24; ++q) {
            const int p = m0 + 4 * q;
            float4 v = make_float4(0.f, 0.f, 0.f, 0.f);
            if (p < T_LEN) v = *reinterpret_cast<const float4*>(row + p);
            w[4*q] = v.x; w[4*q+1] = v.y; w[4*q+2] = v.z; w[4*q+3] = v.w;
        }
    }

    float acc[NCODE + 1];
    #pragma unroll
    for (int k = 0; k <= NCODE; ++k) {
        float a = 0.f;
        #pragma unroll
        for (int j = 0; j < 64; ++j) a = fmaf(w[j], w[j + k], a);
        acc[k] = a;
    }

    #pragma unroll
    for (int k = 0; k <= NCODE; ++k) {
        acc[k] += __shfl_xor(acc[k], 1, 64);
        acc[k] += __shfl_xor(acc[k], 2, 64);
    }

    if (s == 0) {
        #pragma unroll
        for (int q = 0; q < 8; ++q) B[(size_t)q * NG + g] = acc[q];
    } else if (s == 1) {
        #pragma unroll
        for (int q = 0; q < 8; ++q) B[(size_t)(8 + q) * NG + g] = acc[8 + q];
    } else if (s == 2) {
        #pragma unroll
        for (int q = 0; q < 8; ++q) B[(size_t)(16 + q) * NG + g] = acc[16 + q];
    } else {
        #pragma unroll
        for (int q = 0; q < 9; ++q) B[(size_t)(24 + q) * NG + g] = acc[24 + q];
    }
}

__global__ __launch_bounds__(256) void assemble_levinson_kernel(const float* __restrict__ in,
                                                                const float* __restrict__ B,
                                                                float* __restrict__ out) {
    const int t = blockIdx.x * 256 + threadIdx.x;
    if (t >= NFR_TOT) return;
    const int b = t / NFRAMES;
    const int f = t - b * NFRAMES;
    const float* row = in + (size_t)b * T_LEN;
    const int o = f * STRIDE;

    float F[NCODE + 1];
    #pragma unroll
    for (int k = 0; k <= NCODE; ++k) F[k] = 0.f;

    #pragma unroll
    for (int d = 0; d < 4; ++d) {
        const int i = f + d;
        if (i < NBLK) {
            const float* Bp = B + ((size_t)b * NBLK + i);
            #pragma unroll
            for (int k = 0; k <= NCODE; ++k) F[k] += Bp[(size_t)k * NG];
        }
    }

    float a[32], u[32], cx[32];
    auto ld4g = [&](int pos, float* dst) {
        float4 v = make_float4(0.f, 0.f, 0.f, 0.f);
        if (pos < T_LEN) v = *reinterpret_cast<const float4*>(row + pos);
        dst[0] = v.x; dst[1] = v.y; dst[2] = v.z; dst[3] = v.w;
    };
    #pragma unroll
    for (int q = 0; q < 8; ++q) ld4g(o + 4 * q,        &a[4 * q]);
    #pragma unroll
    for (int q = 0; q < 8; ++q) ld4g(o + 992 + 4 * q,  &u[4 * q]);
    #pragma unroll
    for (int q = 0; q < 8; ++q) ld4g(o + 1024 + 4 * q, &cx[4 * q]);

    float dd[32];
    #pragma unroll
    for (int j = 0; j < 32; ++j) dd[j] = a[j] - cx[j];

    float corr[NCODE + 1];
    corr[0] = F[0];
    #pragma unroll
    for (int k = 1; k <= NCODE; ++k) {
        float acc2 = F[k];
        #pragma unroll
        for (int j = 0; j < k; ++j) acc2 = fmaf(u[32 - k + j], dd[j], acc2);
        corr[k] = acc2;
    }

    const float eps = 1e-7f;
    float sol[NCODE + 1];
    const float c0 = fmaxf(corr[0], eps);
    sol[0] = 1.0f;
    sol[1] = -corr[1] / c0;
    float extra = fmaf(corr[1], sol[1], corr[0]);

    #pragma unroll
    for (int k = 1; k < NCODE; ++k) {
        float dot = 0.f;
        #pragma unroll
        for (int i = 0; i <= k; ++i) dot = fmaf(sol[i], corr[k + 1 - i], dot);
        const float lam = -dot / fmaxf(extra, eps);

        float ns[NCODE + 1];
        #pragma unroll
        for (int j = 0; j <= k + 1; ++j) {
            const float av  = (j <= k) ? sol[j] : 0.f;
            const float rev = (j >= 1) ? sol[k + 1 - j] : 0.f;
            ns[j] = fmaf(lam, rev, av);
        }
        #pragma unroll
        for (int j = 0; j <= k + 1; ++j) sol[j] = ns[j];

        extra = (1.f - lam * lam) * extra;
    }

    float* op = out + (size_t)t * NCODE;
    #pragma unroll
    for (int i = 0; i < 8; ++i) {
        *reinterpret_cast<float4*>(op + 4 * i) =
            make_float4(sol[4 * i + 1], sol[4 * i + 2],
                        sol[4 * i + 3], sol[4 * i + 4]);
    }
}

// ---------------------------------------------------------------------------
extern "C" void kernel_launch(void* const* d_in, const int* in_sizes, int n_in,
                              void* d_out, int out_size, void* d_ws, size_t ws_size,
                              hipStream_t stream) {
    const float* in = (const float*)d_in[0];
    float* out      = (float*)d_out;
    float* B        = (float*)d_ws;   // 33 * 65536 * 4 B = 8.65 MB

    // ABLATION: pass 1 launched 4x (identical, deterministic writes).
    // dur(r8) - dur(r3) = 3 * t(pass1).
    for (int rep = 0; rep < 4; ++rep)
        blockprod_kernel<<<NG * 4 / 256, 256, 0, stream>>>(in, B);
    assemble_levinson_kernel<<<(NFR_TOT + 255) / 256, 256, 0, stream>>>(in, B, out);
}

// Round 9
// 42.254 us; speedup vs baseline: 2.4461x; 2.4461x over previous
//
#include <hip/hip_runtime.h>

#define T_LEN   524288
#define BATCH   32
#define WIN     1024
#define STRIDE  256
#define NCODE   32
#define NFRAMES 2049                 // T_LEN/STRIDE + 1
#define NFR_TOT (BATCH * NFRAMES)    // 65568 frames
#define NBLK    2048                 // 256-sample product-blocks per row
#define NG      (BATCH * NBLK)       // 65536 block-product groups
#define FRPW    64                   // frames per pass-2 workgroup
#define XRUNS   68                   // boundary-window runs staged (64 + 4)
#define XSTR    80                   // Xs row stride (dwords): 16B-aligned, 2-way banks
#define BSTR    68                   // Bs row stride (dwords)

// ---------------------------------------------------------------------------
// Pass 1: EXACT r3 kernel (measured 20.5 µs via r8 ablation). Untouched.
// ---------------------------------------------------------------------------
__global__ __launch_bounds__(256) void blockprod_kernel(const float* __restrict__ in,
                                                        float* __restrict__ B) {
    const int tid = blockIdx.x * 256 + threadIdx.x;
    const int g   = tid >> 2;            // (b, i) group
    const int s   = tid & 3;
    const int b   = g >> 11;             // NBLK = 2048
    const int i   = g & (NBLK - 1);
    const float* row = in + (size_t)b * T_LEN;
    const int m0 = i * 256 + s * 64;     // reads [m0, m0+96)

    float w[96];
    if (m0 + 96 <= T_LEN) {
        #pragma unroll
        for (int q = 0; q < 24; ++q) {
            const float4 v = *reinterpret_cast<const float4*>(row + m0 + 4 * q);
            w[4*q] = v.x; w[4*q+1] = v.y; w[4*q+2] = v.z; w[4*q+3] = v.w;
        }
    } else {
        #pragma unroll
        for (int q = 0; q < 24; ++q) {
            const int p = m0 + 4 * q;
            float4 v = make_float4(0.f, 0.f, 0.f, 0.f);
            if (p < T_LEN) v = *reinterpret_cast<const float4*>(row + p);
            w[4*q] = v.x; w[4*q+1] = v.y; w[4*q+2] = v.z; w[4*q+3] = v.w;
        }
    }

    float acc[NCODE + 1];
    #pragma unroll
    for (int k = 0; k <= NCODE; ++k) {
        float a = 0.f;
        #pragma unroll
        for (int j = 0; j < 64; ++j) a = fmaf(w[j], w[j + k], a);
        acc[k] = a;
    }

    #pragma unroll
    for (int k = 0; k <= NCODE; ++k) {
        acc[k] += __shfl_xor(acc[k], 1, 64);
        acc[k] += __shfl_xor(acc[k], 2, 64);
    }

    if (s == 0) {
        #pragma unroll
        for (int q = 0; q < 8; ++q) B[(size_t)q * NG + g] = acc[q];
    } else if (s == 1) {
        #pragma unroll
        for (int q = 0; q < 8; ++q) B[(size_t)(8 + q) * NG + g] = acc[8 + q];
    } else if (s == 2) {
        #pragma unroll
        for (int q = 0; q < 8; ++q) B[(size_t)(16 + q) * NG + g] = acc[16 + q];
    } else {
        #pragma unroll
        for (int q = 0; q < 9; ++q) B[(size_t)(24 + q) * NG + g] = acc[24 + q];
    }
}

// ---------------------------------------------------------------------------
// Pass 2 (v2, cooperative): wg = 256 threads = 64 frames of one row.
//  Phase A (all threads): stage Xs boundary windows + Bs plane slices, coalesced.
//    Xs[r][c] = x[o0 + r*256 - 32 + c] (c 0..63): a[j]=Xs[fl][32+j],
//    u[j]=Xs[fl+4][j], cx[j]=Xs[fl+4][32+j].
//    Bs[k][j] = B[k][b*NBLK + f0 + j] (j 0..67), zero past NBLK.
//  Phase B (wave 0, lane fl = frame): u/dd via b128 from own rows, F[k] from
//    Bs, r3-validated correction + Levinson, guarded float4 stores.
// ---------------------------------------------------------------------------
__global__ __launch_bounds__(256) void assemble_levinson_kernel(const float* __restrict__ in,
                                                                const float* __restrict__ B,
                                                                float* __restrict__ out) {
    __shared__ float Xs[XRUNS * XSTR];   // 21760 B
    __shared__ float Bs[33 * BSTR];      // 8976 B

    const int tid = threadIdx.x;
    const int f0  = blockIdx.x * FRPW;   // 0..2048
    const int b   = blockIdx.y;
    const float* row = in + (size_t)b * T_LEN;
    const long o0 = (long)f0 * STRIDE;

    // ---- Phase A1: stage Xs (68 runs x 64 floats, float4, guarded) ----
    for (int it = tid; it < XRUNS * 16; it += 256) {
        const int r  = it >> 4;
        const int c4 = (it & 15) * 4;
        const long pos = o0 + (long)r * 256 - 32 + c4;   // multiple of 4
        float4 v = make_float4(0.f, 0.f, 0.f, 0.f);
        if (pos >= 0 && pos < T_LEN) v = *reinterpret_cast<const float4*>(row + pos);
        *reinterpret_cast<float4*>(&Xs[r * XSTR + c4]) = v;
    }
    // ---- Phase A2: stage Bs (33 planes x 68 floats, float4, guarded) ----
    for (int it = tid; it < 33 * 17; it += 256) {
        const int k  = it / 17;
        const int c4 = (it - k * 17) * 4;
        const int i0 = f0 + c4;                          // f0 mult of 64 -> aligned
        const float* bp = B + (size_t)k * NG + (size_t)b * NBLK;
        float4 v = make_float4(0.f, 0.f, 0.f, 0.f);
        if (i0 + 3 < NBLK) {
            v = *reinterpret_cast<const float4*>(bp + i0);
        } else {
            float tmp[4] = {0.f, 0.f, 0.f, 0.f};
            #pragma unroll
            for (int e = 0; e < 4; ++e) if (i0 + e < NBLK) tmp[e] = bp[i0 + e];
            v = make_float4(tmp[0], tmp[1], tmp[2], tmp[3]);
        }
        *reinterpret_cast<float4*>(&Bs[k * BSTR + c4]) = v;
    }
    __syncthreads();

    // ---- Phase B: wave 0, one frame per lane ----
    if (tid < FRPW) {
        const int fl = tid;

        float u[32], dd[32];
        #pragma unroll
        for (int q = 0; q < 8; ++q) {
            const float4 va = *reinterpret_cast<const float4*>(&Xs[fl * XSTR + 32 + 4 * q]);
            const float4 vc = *reinterpret_cast<const float4*>(&Xs[(fl + 4) * XSTR + 32 + 4 * q]);
            dd[4*q]   = va.x - vc.x; dd[4*q+1] = va.y - vc.y;
            dd[4*q+2] = va.z - vc.z; dd[4*q+3] = va.w - vc.w;
        }
        #pragma unroll
        for (int q = 0; q < 8; ++q) {
            const float4 vu = *reinterpret_cast<const float4*>(&Xs[(fl + 4) * XSTR + 4 * q]);
            u[4*q] = vu.x; u[4*q+1] = vu.y; u[4*q+2] = vu.z; u[4*q+3] = vu.w;
        }

        float corr[NCODE + 1];
        #pragma unroll
        for (int k = 0; k <= NCODE; ++k) {
            float acc2 = Bs[k * BSTR + fl]     + Bs[k * BSTR + fl + 1]
                       + Bs[k * BSTR + fl + 2] + Bs[k * BSTR + fl + 3];
            #pragma unroll
            for (int j = 0; j < k; ++j) acc2 = fmaf(u[32 - k + j], dd[j], acc2);
            corr[k] = acc2;
        }

        // Levinson-Durbin (r3-validated), fully unrolled -> registers only.
        const float eps = 1e-7f;
        float sol[NCODE + 1];
        const float c0 = fmaxf(corr[0], eps);
        sol[0] = 1.0f;
        sol[1] = -corr[1] / c0;
        float extra = fmaf(corr[1], sol[1], corr[0]);

        #pragma unroll
        for (int k = 1; k < NCODE; ++k) {
            float dot = 0.f;
            #pragma unroll
            for (int i = 0; i <= k; ++i) dot = fmaf(sol[i], corr[k + 1 - i], dot);
            const float lam = -dot / fmaxf(extra, eps);

            float ns[NCODE + 1];
            #pragma unroll
            for (int j = 0; j <= k + 1; ++j) {
                const float av  = (j <= k) ? sol[j] : 0.f;
                const float rev = (j >= 1) ? sol[k + 1 - j] : 0.f;
                ns[j] = fmaf(lam, rev, av);
            }
            #pragma unroll
            for (int j = 0; j <= k + 1; ++j) sol[j] = ns[j];

            extra = (1.f - lam * lam) * extra;
        }

        const int frame = f0 + fl;
        if (frame < NFRAMES) {
            float* op = out + ((size_t)b * NFRAMES + frame) * NCODE;
            #pragma unroll
            for (int i = 0; i < 8; ++i) {
                *reinterpret_cast<float4*>(op + 4 * i) =
                    make_float4(sol[4*i + 1], sol[4*i + 2], sol[4*i + 3], sol[4*i + 4]);
            }
        }
    }
}

// ---------------------------------------------------------------------------
extern "C" void kernel_launch(void* const* d_in, const int* in_sizes, int n_in,
                              void* d_out, int out_size, void* d_ws, size_t ws_size,
                              hipStream_t stream) {
    const float* in = (const float*)d_in[0];
    float* out      = (float*)d_out;
    float* B        = (float*)d_ws;   // 33 * 65536 * 4 B = 8.65 MB

    blockprod_kernel<<<NG * 4 / 256, 256, 0, stream>>>(in, B);   // 1024 wgs

    dim3 g2((NFRAMES + FRPW - 1) / FRPW, BATCH);                 // 33 x 32 wgs
    assemble_levinson_kernel<<<g2, 256, 0, stream>>>(in, B, out);
}